// Round 16
// baseline (33.365 us; speedup 1.0000x reference)
//
#include <hip/hip_runtime.h>

#define Bn 16
#define Hn 512
#define Wn 512
#define RAD 16
#define WPR 16  // 32-bit words per row (Wn/32)

typedef _Float16 h2 __attribute__((ext_vector_type(2)));

// ---------------------------------------------------------------------------
// K0: fused binarize + morphology + transpose (proven). Block = (b, 32-row
// group w), 1024 threads. Block 0 zeroes the atomic tree.
// ---------------------------------------------------------------------------
__global__ __launch_bounds__(1024) void k_prep(
    const float* __restrict__ tgt, unsigned int* __restrict__ mbits,
    unsigned int* __restrict__ cbits, unsigned long long* __restrict__ grp,
    unsigned int* __restrict__ supercnt) {
  __shared__ int nib[4608];             // 36 rows x 128 nibbles
  __shared__ unsigned int lm[36][16];   // mask words, rows y0-2..y0+33
  __shared__ unsigned int bnd[32][17];  // boundary bits, padded
  const int w = blockIdx.x & 15, b = blockIdx.x >> 4;
  const int y0 = w * 32;
  const int t = threadIdx.x;
  const float4* t4 = (const float4*)(tgt + (size_t)b * Hn * Wn);

  if (blockIdx.x == 0) {  // zero atomic tree (visible via kernel-end release)
    if (t < 64) grp[t * 8] = 0ull;
    else if (t == 64) *supercnt = 0u;
  }

  for (int idx = t; idx < 4608; idx += 1024) {
    int r = idx >> 7, c4 = idx & 127;
    int y = y0 - 2 + r;
    int n = 0;
    if (y >= 0 && y < Hn) {
      float4 v = t4[(size_t)y * 128 + c4];
      n = (v.x > 0.5f ? 1 : 0) | (v.y > 0.5f ? 2 : 0) |
          (v.z > 0.5f ? 4 : 0) | (v.w > 0.5f ? 8 : 0);
    }
    nib[idx] = n;
  }
  __syncthreads();

  for (int idx = t; idx < 576; idx += 1024) {
    int r = idx >> 4, wi = idx & 15;
    unsigned int wv = 0;
#pragma unroll
    for (int c = 0; c < 8; ++c)
      wv |= ((unsigned int)nib[(r << 7) + (wi << 3) + c]) << (4 * c);
    lm[r][wi] = wv;
  }
  __syncthreads();

  if (t < 512) {
    int rr = t >> 4, k = t & 15;  // output row y0+rr, word k
    unsigned int m[5][5];
#pragma unroll
    for (int dy = 0; dy < 5; ++dy)
#pragma unroll
      for (int dx = 0; dx < 5; ++dx) {
        int wi = k + dx - 2;
        m[dy][dx] = (wi >= 0 && wi < 16) ? lm[rr + dy][wi] : 0u;
      }
    unsigned int hb[5][3];
#pragma unroll
    for (int dy = 0; dy < 5; ++dy)
#pragma unroll
      for (int dx = 0; dx < 3; ++dx) {
        unsigned int l = m[dy][dx], c = m[dy][dx + 1], r2 = m[dy][dx + 2];
        hb[dy][dx] = c & ((c << 1) | (l >> 31)) & ((c >> 1) | (r2 << 31));
      }
    unsigned int D = 0;
#pragma unroll
    for (int dy = 1; dy <= 3; ++dy) {
      unsigned int C[3];
#pragma unroll
      for (int dx = 0; dx < 3; ++dx) {
        unsigned int E = hb[dy - 1][dx] & hb[dy][dx] & hb[dy + 1][dx];
        C[dx] = m[dy][dx + 1] & ~E;
      }
      D |= C[1] | ((C[1] << 1) | (C[0] >> 31)) | ((C[1] >> 1) | (C[2] << 31));
    }
    bnd[rr][k] = D;
  } else {
    int task = t - 512;
    int r = task >> 4, wi = task & 15;
    mbits[((size_t)b * Hn + y0 + r) * WPR + wi] = lm[2 + r][wi];
  }
  __syncthreads();

  if (t < 512) {
    int col = t;
    unsigned int bw = 0;
#pragma unroll
    for (int r = 0; r < 32; ++r)
      bw |= ((bnd[r][col >> 5] >> (col & 31)) & 1u) << r;
    cbits[((size_t)b * WPR + w) * Wn + col] = bw;
  }
}

// ---------------------------------------------------------------------------
// vertical distance from column bit-words (5 words cover rows i-64..i+95)
// ---------------------------------------------------------------------------
__device__ __forceinline__ int dv_from(unsigned int W0, unsigned int W1,
                                       unsigned int W2, unsigned int W3,
                                       unsigned int W4, int q) {
  unsigned int mLE = (q == 31) ? W2 : (W2 & ((1u << (q + 1)) - 1u));
  int up = mLE ? (q - 31 + __clz(mLE))
               : (W1 ? (q + 1 + __clz(W1))
                     : (W0 ? (q + 33 + __clz(W0)) : 255));
  unsigned int Wd = W2 >> q;
  int down = Wd ? (__ffs(Wd) - 1)
                : (W3 ? (31 - q + __ffs(W3))
                      : (W4 ? (63 - q + __ffs(W4)) : 255));
  return min(up, down);
}

// ---------------------------------------------------------------------------
// K1: chamfer window, 16 rows/block (eight h2 pairs), wave-uniform early
// exit, BCE, two-level spread atomic finisher. 1024 blocks.
// ---------------------------------------------------------------------------
__global__ __launch_bounds__(256, 4) void k_loss(
    const float* __restrict__ x, const unsigned int* __restrict__ mbits,
    const unsigned int* __restrict__ cbits,
    unsigned long long* __restrict__ grp, unsigned int* __restrict__ supercnt,
    float* __restrict__ out) {
  __shared__ h2 dvs[8][288];  // pair p: rows (i0+2p, i0+2p+1)
  __shared__ float red[4];
  __shared__ unsigned long long lred[64];
  __shared__ int leader;
  const int cx = blockIdx.x, by = blockIdx.y, b = blockIdx.z;
  const int i0 = 16 * by;
  const int c0 = cx * 256;
  const int tx = threadIdx.x;
  const size_t row0 = ((size_t)b * Hn + i0) * Wn;
  const int wq = i0 >> 5, q = i0 & 31;  // q in {0,16}; q+15 <= 31
  const unsigned int* cw = cbits + (size_t)b * WPR * Wn;

  // issue x / mbits loads early; they retire under the prologue/window
  const int col = c0 + tx;
  float L[16];
#pragma unroll
  for (int r = 0; r < 16; ++r) L[r] = x[row0 + (size_t)r * Wn + col];
  const int wi = col >> 5, sh = col & 31;
  const size_t mrow = ((size_t)b * Hn + i0) * WPR + wi;
  unsigned int mw[16];
#pragma unroll
  for (int r = 0; r < 16; ++r) mw[r] = mbits[mrow + (size_t)r * WPR];

  for (int e = tx; e < 288; e += 256) {
    int c = c0 + e - RAD;
    int dv[16];
#pragma unroll
    for (int r = 0; r < 16; ++r) dv[r] = 255;
    if (c >= 0 && c < Wn) {
      unsigned int W0 = (wq >= 2) ? cw[(size_t)(wq - 2) * Wn + c] : 0u;
      unsigned int W1 = (wq >= 1) ? cw[(size_t)(wq - 1) * Wn + c] : 0u;
      unsigned int W2 = cw[(size_t)wq * Wn + c];
      unsigned int W3 = (wq <= 14) ? cw[(size_t)(wq + 1) * Wn + c] : 0u;
      unsigned int W4 = (wq <= 13) ? cw[(size_t)(wq + 2) * Wn + c] : 0u;
#pragma unroll
      for (int r = 0; r < 16; ++r) dv[r] = dv_from(W0, W1, W2, W3, W4, q + r);
    }
#pragma unroll
    for (int p = 0; p < 8; ++p) {
      h2 pk;
      pk.x = (_Float16)(float)dv[2 * p];
      pk.y = (_Float16)(float)dv[2 * p + 1];
      dvs[p][e] = pk;
    }
  }
  __syncthreads();

  const h2 A2 = {(_Float16)0.955f, (_Float16)0.955f};
  const h2 BA2 = {(_Float16)0.4143f, (_Float16)0.4143f};
  h2 acc0[8], acc1[8];
#pragma unroll
  for (int p = 0; p < 8; ++p) {
    acc0[p].x = (_Float16)300.0f;
    acc0[p].y = (_Float16)300.0f;
    acc1[p] = acc0[p];
  }

#define STEP(k)                                                              \
  {                                                                          \
    const h2 c1 = {(_Float16)(0.955f * (k)), (_Float16)(0.955f * (k))};      \
    const h2 c2 = {(_Float16)(0.4143f * (k)), (_Float16)(0.4143f * (k))};    \
    _Pragma("unroll") for (int p = 0; p < 8; ++p) {                          \
      h2 v = __builtin_elementwise_min(dvs[p][tx + RAD - (k)],               \
                                       dvs[p][tx + RAD + (k)]);              \
      h2 f = __builtin_elementwise_max(v * BA2 + c1, v * A2 + c2);           \
      if ((k) & 1) acc1[p] = __builtin_elementwise_min(acc1[p], f);          \
      else         acc0[p] = __builtin_elementwise_min(acc0[p], f);          \
    }                                                                        \
  }

#define CHECK(kn)                                                            \
  {                                                                          \
    h2 qq = __builtin_elementwise_min(acc0[0], acc1[0]);                     \
    _Pragma("unroll") for (int p = 1; p < 8; ++p) {                          \
      qq = __builtin_elementwise_min(                                        \
          qq, __builtin_elementwise_min(acc0[p], acc1[p]));                  \
    }                                                                        \
    float mm = fmaxf((float)qq.x, (float)qq.y);                              \
    for (int s = 1; s < 64; s <<= 1) mm = fmaxf(mm, __shfl_xor(mm, s, 64));  \
    if (0.955f * (float)(kn) >= mm) goto done_lab;                           \
  }

  STEP(0) STEP(1) STEP(2) STEP(3) STEP(4)
  CHECK(5)
  STEP(5) STEP(6) STEP(7) STEP(8)
  CHECK(9)
  STEP(9) STEP(10) STEP(11) STEP(12)
  CHECK(13)
  STEP(13) STEP(14) STEP(15) STEP(16)
done_lab:;

  {
    float val = 0.0f;
#pragma unroll
    for (int p = 0; p < 8; ++p) {
      h2 am = __builtin_elementwise_min(acc0[p], acc1[p]);
      float dlo = (float)am.x, dhi = (float)am.y;
      float wlo = __expf(dlo * (-1.0f / 3.0f)) + 0.1f;
      float whi = __expf(dhi * (-1.0f / 3.0f)) + 0.1f;
      float tlo = (float)((mw[2 * p] >> sh) & 1u);
      float thi = (float)((mw[2 * p + 1] >> sh) & 1u);
      float Llo = fminf(fmaxf(L[2 * p], -16.118095f), 16.118095f);
      float Lhi = fminf(fmaxf(L[2 * p + 1], -16.118095f), 16.118095f);
      float blo = fmaxf(Llo, 0.0f) - Llo * tlo +
                  __logf(1.0f + __expf(-fabsf(Llo)));
      float bhi = fmaxf(Lhi, 0.0f) - Lhi * thi +
                  __logf(1.0f + __expf(-fabsf(Lhi)));
      val += blo * wlo + bhi * whi;
    }

#pragma unroll
    for (int s = 32; s; s >>= 1) val += __shfl_down(val, s, 64);
    if ((tx & 63) == 0) red[tx >> 6] = val;
  }
  __syncthreads();

  if (tx == 0) {
    leader = 0;
    float s = red[0] + red[1] + red[2] + red[3];
    // fixed-point (2^20) partial. Per-group sum < 2^45; count in bits 52+.
    unsigned long long qv =
        (unsigned long long)__double2ll_rn((double)s * 1048576.0);
    const int u = (((b << 5) + by) << 1) + cx;  // 0..1023
    unsigned long long old = atomicAdd(&grp[(u & 63) * 8], qv + (1ull << 52));
    if ((old >> 52) == 15ull) {  // 16 blocks per group
      unsigned int os = atomicAdd(supercnt, 1u);
      if (os == 63u) leader = 1;
    }
  }
  __syncthreads();

  if (leader) {
    if (tx < 64) {  // 64 parallel atomic reads (complete values guaranteed)
      unsigned long long v = atomicAdd(&grp[tx * 8], 0ull);
      lred[tx] = v & ((1ull << 52) - 1ull);
    }
    __syncthreads();
    if (tx == 0) {
      unsigned long long sum = 0ull;
#pragma unroll
      for (int i = 0; i < 64; ++i) sum += lred[i];
      out[0] =
          (float)((double)sum / (1048576.0 * (double)((size_t)Bn * Hn * Wn)));
    }
  }
}

extern "C" void kernel_launch(void* const* d_in, const int* in_sizes, int n_in,
                              void* d_out, int out_size, void* d_ws, size_t ws_size,
                              hipStream_t stream) {
  const float* inputs = (const float*)d_in[0];
  const float* targets = (const float*)d_in[1];
  float* out = (float*)d_out;

  unsigned char* ws = (unsigned char*)d_ws;
  unsigned int* mbits = (unsigned int*)ws;                          // 512 KB
  unsigned int* cbits = (unsigned int*)(ws + (512 << 10));          // 512 KB
  unsigned long long* grp = (unsigned long long*)(ws + (1 << 20));  // 4 KB
  unsigned int* supercnt = (unsigned int*)(ws + (1 << 20) + 4096);

  hipLaunchKernelGGL(k_prep, dim3(Bn * 16), dim3(1024), 0, stream, targets,
                     mbits, cbits, grp, supercnt);
  {
    dim3 blk(256, 1, 1), grd(2, Hn / 16, Bn);
    hipLaunchKernelGGL(k_loss, grd, blk, 0, stream, inputs, mbits, cbits, grp,
                       supercnt, out);
  }
}

// Round 17
// 28.959 us; speedup vs baseline: 1.1521x; 1.1521x over previous
//
#include <hip/hip_runtime.h>

#define Bn 16
#define Hn 512
#define Wn 512
#define RAD 16
#define WPR 16  // 32-bit words per row (Wn/32)

typedef _Float16 h2 __attribute__((ext_vector_type(2)));

// ---------------------------------------------------------------------------
// K0: fused binarize + morphology + transpose (proven). Block = (b, 32-row
// group w), 1024 threads. Block 0 zeroes the atomic tree.
// ---------------------------------------------------------------------------
__global__ __launch_bounds__(1024) void k_prep(
    const float* __restrict__ tgt, unsigned int* __restrict__ mbits,
    unsigned int* __restrict__ cbits, unsigned long long* __restrict__ grp,
    unsigned int* __restrict__ supercnt) {
  __shared__ int nib[4608];             // 36 rows x 128 nibbles
  __shared__ unsigned int lm[36][16];   // mask words, rows y0-2..y0+33
  __shared__ unsigned int bnd[32][17];  // boundary bits, padded
  const int w = blockIdx.x & 15, b = blockIdx.x >> 4;
  const int y0 = w * 32;
  const int t = threadIdx.x;
  const float4* t4 = (const float4*)(tgt + (size_t)b * Hn * Wn);

  if (blockIdx.x == 0) {  // zero atomic tree (visible via kernel-end release)
    if (t < 64) grp[t * 8] = 0ull;
    else if (t == 64) *supercnt = 0u;
  }

  for (int idx = t; idx < 4608; idx += 1024) {
    int r = idx >> 7, c4 = idx & 127;
    int y = y0 - 2 + r;
    int n = 0;
    if (y >= 0 && y < Hn) {
      float4 v = t4[(size_t)y * 128 + c4];
      n = (v.x > 0.5f ? 1 : 0) | (v.y > 0.5f ? 2 : 0) |
          (v.z > 0.5f ? 4 : 0) | (v.w > 0.5f ? 8 : 0);
    }
    nib[idx] = n;
  }
  __syncthreads();

  for (int idx = t; idx < 576; idx += 1024) {
    int r = idx >> 4, wi = idx & 15;
    unsigned int wv = 0;
#pragma unroll
    for (int c = 0; c < 8; ++c)
      wv |= ((unsigned int)nib[(r << 7) + (wi << 3) + c]) << (4 * c);
    lm[r][wi] = wv;
  }
  __syncthreads();

  if (t < 512) {
    int rr = t >> 4, k = t & 15;  // output row y0+rr, word k
    unsigned int m[5][5];
#pragma unroll
    for (int dy = 0; dy < 5; ++dy)
#pragma unroll
      for (int dx = 0; dx < 5; ++dx) {
        int wi = k + dx - 2;
        m[dy][dx] = (wi >= 0 && wi < 16) ? lm[rr + dy][wi] : 0u;
      }
    unsigned int hb[5][3];
#pragma unroll
    for (int dy = 0; dy < 5; ++dy)
#pragma unroll
      for (int dx = 0; dx < 3; ++dx) {
        unsigned int l = m[dy][dx], c = m[dy][dx + 1], r2 = m[dy][dx + 2];
        hb[dy][dx] = c & ((c << 1) | (l >> 31)) & ((c >> 1) | (r2 << 31));
      }
    unsigned int D = 0;
#pragma unroll
    for (int dy = 1; dy <= 3; ++dy) {
      unsigned int C[3];
#pragma unroll
      for (int dx = 0; dx < 3; ++dx) {
        unsigned int E = hb[dy - 1][dx] & hb[dy][dx] & hb[dy + 1][dx];
        C[dx] = m[dy][dx + 1] & ~E;
      }
      D |= C[1] | ((C[1] << 1) | (C[0] >> 31)) | ((C[1] >> 1) | (C[2] << 31));
    }
    bnd[rr][k] = D;
  } else {
    int task = t - 512;
    int r = task >> 4, wi = task & 15;
    mbits[((size_t)b * Hn + y0 + r) * WPR + wi] = lm[2 + r][wi];
  }
  __syncthreads();

  if (t < 512) {
    int col = t;
    unsigned int bw = 0;
#pragma unroll
    for (int r = 0; r < 32; ++r)
      bw |= ((bnd[r][col >> 5] >> (col & 31)) & 1u) << r;
    cbits[((size_t)b * WPR + w) * Wn + col] = bw;
  }
}

// ---------------------------------------------------------------------------
// vertical distance from column bit-words (5 words cover rows i-64..i+95)
// ---------------------------------------------------------------------------
__device__ __forceinline__ int dv_from(unsigned int W0, unsigned int W1,
                                       unsigned int W2, unsigned int W3,
                                       unsigned int W4, int q) {
  unsigned int mLE = (q == 31) ? W2 : (W2 & ((1u << (q + 1)) - 1u));
  int up = mLE ? (q - 31 + __clz(mLE))
               : (W1 ? (q + 1 + __clz(W1))
                     : (W0 ? (q + 33 + __clz(W0)) : 255));
  unsigned int Wd = W2 >> q;
  int down = Wd ? (__ffs(Wd) - 1)
                : (W3 ? (31 - q + __ffs(W3))
                      : (W4 ? (63 - q + __ffs(W4)) : 255));
  return min(up, down);
}

// ---------------------------------------------------------------------------
// K1: chamfer window, 8 rows/block (four h2 pairs), wave-uniform early exit,
// BCE, two-level spread atomic finisher. 2048 blocks. (Round-15 optimum.)
// ---------------------------------------------------------------------------
__global__ __launch_bounds__(256) void k_loss(
    const float* __restrict__ x, const unsigned int* __restrict__ mbits,
    const unsigned int* __restrict__ cbits,
    unsigned long long* __restrict__ grp, unsigned int* __restrict__ supercnt,
    float* __restrict__ out) {
  __shared__ h2 dvsA[288];  // rows (i0,   i0+1)
  __shared__ h2 dvsB[288];  // rows (i0+2, i0+3)
  __shared__ h2 dvsC[288];  // rows (i0+4, i0+5)
  __shared__ h2 dvsD[288];  // rows (i0+6, i0+7)
  __shared__ float red[4];
  __shared__ unsigned long long lred[64];
  __shared__ int leader;
  const int cx = blockIdx.x, by = blockIdx.y, b = blockIdx.z;
  const int i0 = 8 * by;
  const int c0 = cx * 256;
  const int tx = threadIdx.x;
  const size_t row0 = ((size_t)b * Hn + i0) * Wn;
  const int wq = i0 >> 5, q = i0 & 31;  // q in {0,8,16,24}; q+7 <= 31
  const unsigned int* cw = cbits + (size_t)b * WPR * Wn;

  // issue x / mbits loads early; they retire under the prologue/window
  const int col = c0 + tx;
  float L[8];
#pragma unroll
  for (int r = 0; r < 8; ++r) L[r] = x[row0 + (size_t)r * Wn + col];
  const int wi = col >> 5, sh = col & 31;
  const size_t mrow = ((size_t)b * Hn + i0) * WPR + wi;
  unsigned int mw[8];
#pragma unroll
  for (int r = 0; r < 8; ++r) mw[r] = mbits[mrow + (size_t)r * WPR];

  for (int e = tx; e < 288; e += 256) {
    int c = c0 + e - RAD;
    int dv[8];
#pragma unroll
    for (int r = 0; r < 8; ++r) dv[r] = 255;
    if (c >= 0 && c < Wn) {
      unsigned int W0 = (wq >= 2) ? cw[(size_t)(wq - 2) * Wn + c] : 0u;
      unsigned int W1 = (wq >= 1) ? cw[(size_t)(wq - 1) * Wn + c] : 0u;
      unsigned int W2 = cw[(size_t)wq * Wn + c];
      unsigned int W3 = (wq <= 14) ? cw[(size_t)(wq + 1) * Wn + c] : 0u;
      unsigned int W4 = (wq <= 13) ? cw[(size_t)(wq + 2) * Wn + c] : 0u;
#pragma unroll
      for (int r = 0; r < 8; ++r) dv[r] = dv_from(W0, W1, W2, W3, W4, q + r);
    }
    h2 p;
    p.x = (_Float16)(float)dv[0]; p.y = (_Float16)(float)dv[1]; dvsA[e] = p;
    p.x = (_Float16)(float)dv[2]; p.y = (_Float16)(float)dv[3]; dvsB[e] = p;
    p.x = (_Float16)(float)dv[4]; p.y = (_Float16)(float)dv[5]; dvsC[e] = p;
    p.x = (_Float16)(float)dv[6]; p.y = (_Float16)(float)dv[7]; dvsD[e] = p;
  }
  __syncthreads();

  const h2 A2 = {(_Float16)0.955f, (_Float16)0.955f};
  const h2 BA2 = {(_Float16)0.4143f, (_Float16)0.4143f};
  h2 a0 = {(_Float16)300.0f, (_Float16)300.0f};
  h2 a1 = a0, b0 = a0, b1 = a0, c0a = a0, c1a = a0, d0a = a0, d1a = a0;

#define STEP(k)                                                              \
  {                                                                          \
    const h2 c1 = {(_Float16)(0.955f * (k)), (_Float16)(0.955f * (k))};      \
    const h2 c2 = {(_Float16)(0.4143f * (k)), (_Float16)(0.4143f * (k))};    \
    h2 vA = __builtin_elementwise_min(dvsA[tx + RAD - (k)],                  \
                                      dvsA[tx + RAD + (k)]);                 \
    h2 vB = __builtin_elementwise_min(dvsB[tx + RAD - (k)],                  \
                                      dvsB[tx + RAD + (k)]);                 \
    h2 vC = __builtin_elementwise_min(dvsC[tx + RAD - (k)],                  \
                                      dvsC[tx + RAD + (k)]);                 \
    h2 vD = __builtin_elementwise_min(dvsD[tx + RAD - (k)],                  \
                                      dvsD[tx + RAD + (k)]);                 \
    h2 fA = __builtin_elementwise_max(vA * BA2 + c1, vA * A2 + c2);          \
    h2 fB = __builtin_elementwise_max(vB * BA2 + c1, vB * A2 + c2);          \
    h2 fC = __builtin_elementwise_max(vC * BA2 + c1, vC * A2 + c2);          \
    h2 fD = __builtin_elementwise_max(vD * BA2 + c1, vD * A2 + c2);          \
    if ((k) & 1) {                                                           \
      a1 = __builtin_elementwise_min(a1, fA);                                \
      b1 = __builtin_elementwise_min(b1, fB);                                \
      c1a = __builtin_elementwise_min(c1a, fC);                              \
      d1a = __builtin_elementwise_min(d1a, fD);                              \
    } else {                                                                 \
      a0 = __builtin_elementwise_min(a0, fA);                                \
      b0 = __builtin_elementwise_min(b0, fB);                                \
      c0a = __builtin_elementwise_min(c0a, fC);                              \
      d0a = __builtin_elementwise_min(d0a, fD);                              \
    }                                                                        \
  }

#define CHECK(kn)                                                            \
  {                                                                          \
    h2 qa = __builtin_elementwise_min(a0, a1);                               \
    h2 qb = __builtin_elementwise_min(b0, b1);                               \
    h2 qc = __builtin_elementwise_min(c0a, c1a);                             \
    h2 qd = __builtin_elementwise_min(d0a, d1a);                             \
    h2 qq = __builtin_elementwise_min(__builtin_elementwise_min(qa, qb),     \
                                      __builtin_elementwise_min(qc, qd));    \
    float mm = fmaxf((float)qq.x, (float)qq.y);                              \
    for (int s = 1; s < 64; s <<= 1) mm = fmaxf(mm, __shfl_xor(mm, s, 64));  \
    if (0.955f * (float)(kn) >= mm) goto done_lab;                           \
  }

  STEP(0) STEP(1) STEP(2) STEP(3) STEP(4)
  CHECK(5)
  STEP(5) STEP(6) STEP(7) STEP(8)
  CHECK(9)
  STEP(9) STEP(10) STEP(11) STEP(12)
  CHECK(13)
  STEP(13) STEP(14) STEP(15) STEP(16)
done_lab:;

  {
    h2 am[4];
    am[0] = __builtin_elementwise_min(a0, a1);
    am[1] = __builtin_elementwise_min(b0, b1);
    am[2] = __builtin_elementwise_min(c0a, c1a);
    am[3] = __builtin_elementwise_min(d0a, d1a);

    float val = 0.0f;
#pragma unroll
    for (int p = 0; p < 4; ++p) {
      float dlo = (float)am[p].x, dhi = (float)am[p].y;
      float wlo = __expf(dlo * (-1.0f / 3.0f)) + 0.1f;
      float whi = __expf(dhi * (-1.0f / 3.0f)) + 0.1f;
      float tlo = (float)((mw[2 * p] >> sh) & 1u);
      float thi = (float)((mw[2 * p + 1] >> sh) & 1u);
      float Llo = fminf(fmaxf(L[2 * p], -16.118095f), 16.118095f);
      float Lhi = fminf(fmaxf(L[2 * p + 1], -16.118095f), 16.118095f);
      float blo = fmaxf(Llo, 0.0f) - Llo * tlo +
                  __logf(1.0f + __expf(-fabsf(Llo)));
      float bhi = fmaxf(Lhi, 0.0f) - Lhi * thi +
                  __logf(1.0f + __expf(-fabsf(Lhi)));
      val += blo * wlo + bhi * whi;
    }

#pragma unroll
    for (int s = 32; s; s >>= 1) val += __shfl_down(val, s, 64);
    if ((tx & 63) == 0) red[tx >> 6] = val;
  }
  __syncthreads();

  if (tx == 0) {
    leader = 0;
    float s = red[0] + red[1] + red[2] + red[3];
    // fixed-point (2^20) partial. Per-group sum < 2^41; count in bits 52+.
    unsigned long long qv =
        (unsigned long long)__double2ll_rn((double)s * 1048576.0);
    const int u = (((b << 6) + by) << 1) + cx;  // 0..2047
    unsigned long long old = atomicAdd(&grp[(u & 63) * 8], qv + (1ull << 52));
    if ((old >> 52) == 31ull) {  // 32 blocks per group
      unsigned int os = atomicAdd(supercnt, 1u);
      if (os == 63u) leader = 1;
    }
  }
  __syncthreads();

  if (leader) {
    if (tx < 64) {  // 64 parallel atomic reads (complete values guaranteed)
      unsigned long long v = atomicAdd(&grp[tx * 8], 0ull);
      lred[tx] = v & ((1ull << 52) - 1ull);
    }
    __syncthreads();
    if (tx == 0) {
      unsigned long long sum = 0ull;
#pragma unroll
      for (int i = 0; i < 64; ++i) sum += lred[i];
      out[0] =
          (float)((double)sum / (1048576.0 * (double)((size_t)Bn * Hn * Wn)));
    }
  }
}

extern "C" void kernel_launch(void* const* d_in, const int* in_sizes, int n_in,
                              void* d_out, int out_size, void* d_ws, size_t ws_size,
                              hipStream_t stream) {
  const float* inputs = (const float*)d_in[0];
  const float* targets = (const float*)d_in[1];
  float* out = (float*)d_out;

  unsigned char* ws = (unsigned char*)d_ws;
  unsigned int* mbits = (unsigned int*)ws;                          // 512 KB
  unsigned int* cbits = (unsigned int*)(ws + (512 << 10));          // 512 KB
  unsigned long long* grp = (unsigned long long*)(ws + (1 << 20));  // 4 KB
  unsigned int* supercnt = (unsigned int*)(ws + (1 << 20) + 4096);

  hipLaunchKernelGGL(k_prep, dim3(Bn * 16), dim3(1024), 0, stream, targets,
                     mbits, cbits, grp, supercnt);
  {
    dim3 blk(256, 1, 1), grd(2, Hn / 8, Bn);
    hipLaunchKernelGGL(k_loss, grd, blk, 0, stream, inputs, mbits, cbits, grp,
                       supercnt, out);
  }
}